// Round 8
// baseline (940.731 us; speedup 1.0000x reference)
//
#include <hip/hip_runtime.h>
#include <hip/hip_bf16.h>

// Sizes (fixed): B=64 T=128 HID=512 LOC_EMB=256 TIM_EMB=64 UID_EMB=128
// L_HIST=1024 G=4, K_x=320, K_attn=448, N_gates=1536, UID_SIZE=5000

typedef __attribute__((ext_vector_type(8))) short bf16x8;
typedef __attribute__((ext_vector_type(4))) float f32x4;
typedef __attribute__((ext_vector_type(4))) unsigned short u16x4;
typedef __attribute__((ext_vector_type(2))) unsigned long long u64x2;
typedef unsigned long long u64;

#define GXB 96   // gemm_gx blocks
#define ATB 44   // gemm_attn blocks
#define GRUB 32  // gru blocks (4 waves each)

__device__ inline unsigned short f2bf(float x) {
  __hip_bfloat16 b = __float2bfloat16(x);
  return __builtin_bit_cast(unsigned short, b);
}
__device__ inline bf16x8 pack8(float4 a, float4 b) {
  bf16x8 w;
  w[0]=(short)f2bf(a.x); w[1]=(short)f2bf(a.y); w[2]=(short)f2bf(a.z); w[3]=(short)f2bf(a.w);
  w[4]=(short)f2bf(b.x); w[5]=(short)f2bf(b.y); w[6]=(short)f2bf(b.z); w[7]=(short)f2bf(b.w);
  return w;
}

// ============ phase1 megakernel ============
// sync layout (dwords): [0,512) = gru flags (2 gp x 16 x 16dw);
//                       [512,576) = done[yt] for gx tiles; [576] = gx total.
__global__ __launch_bounds__(256)
void phase1(const int* __restrict__ loc, const int* __restrict__ tim,
            const int* __restrict__ lens,
            const int* __restrict__ hloc, const int* __restrict__ htim,
            const int* __restrict__ huid,
            const float* __restrict__ eloc, const float* __restrict__ etim,
            const float* __restrict__ euid,
            const float* __restrict__ W_attn, const float* __restrict__ b_attn,
            const float* __restrict__ W_ih, const float* __restrict__ b_ih,
            const float* __restrict__ W_hh, const float* __restrict__ b_hh,
            float* __restrict__ gx, float* __restrict__ histt,
            short* __restrict__ h_bf, float* __restrict__ lastb,
            unsigned int* __restrict__ sync) {
  __shared__ short smem[6 * 16 * 512];   // 96 KB, shared by all roles
  const int bid = blockIdx.x;
  const int tid = threadIdx.x;

  if (bid < GXB + ATB) {
    // ================= GEMM roles (gather-fused, bf16 MFMA) =================
    constexpr int LDR = 40;              // padded LDS row stride (shorts)
    short* Asl = smem;
    short* Bsl = smem + 128 * LDR;
    const int lane = tid & 63, wid = tid >> 6;
    const int wr = wid >> 1, wc = wid & 1;
    const int m16 = lane & 15, g4 = lane >> 4;
    const int srow = tid >> 1, shalf = tid & 1;
    const bool isgx = bid < GXB;
    const int ntiles = isgx ? 768 : 512;       // 64yt x 12nt ; 128yt x 4nt
    const int stride = isgx ? GXB : ATB;
    const int NT     = isgx ? 12 : 4;
    const int Kdim   = isgx ? 320 : 448;
    const int Ndim   = isgx ? 1536 : 512;
    const float* Bmat = isgx ? W_ih : W_attn;
    const float* bias = isgx ? b_ih : b_attn;
    for (int tile = isgx ? bid : (bid - GXB); tile < ntiles; tile += stride) {
      const int yt = tile / NT, nt = tile % NT;
      const int bm = yt << 7, bn = nt << 7;
      f32x4 acc[4][4] = {};
      for (int k0 = 0; k0 < Kdim; k0 += 32) {
        // ---- stage A (gathered from embeddings) ----
        {
          const int grow = bm + srow;
          float4 f0, f1, f2, f3;
          if (isgx) {
            const int t = grow >> 6, b = grow & 63;
            const float* ap = (k0 < 256)
              ? eloc + (size_t)loc[b * 128 + t] * 256 + k0 + (shalf << 4)
              : etim + (size_t)tim[b * 128 + t] * 64 + (k0 - 256) + (shalf << 4);
            f0 = ((const float4*)ap)[0]; f1 = ((const float4*)ap)[1];
            f2 = ((const float4*)ap)[2]; f3 = ((const float4*)ap)[3];
          } else {
            const int b = grow >> 8, n = grow & 255;
            const int base = b * 1024 + (n << 2);
            if (k0 < 256) {
              const float* ap = eloc + (size_t)hloc[base] * 256 + k0 + (shalf << 4);
              f0 = ((const float4*)ap)[0]; f1 = ((const float4*)ap)[1];
              f2 = ((const float4*)ap)[2]; f3 = ((const float4*)ap)[3];
            } else if (k0 < 320) {
              const float* ap = etim + (size_t)htim[base] * 64 + (k0 - 256) + (shalf << 4);
              f0 = ((const float4*)ap)[0]; f1 = ((const float4*)ap)[1];
              f2 = ((const float4*)ap)[2]; f3 = ((const float4*)ap)[3];
            } else {
              const int cu = (k0 - 320) + (shalf << 4);
              const float4* u0 = (const float4*)(euid + (size_t)huid[base + 0] * 128 + cu);
              const float4* u1 = (const float4*)(euid + (size_t)huid[base + 1] * 128 + cu);
              const float4* u2 = (const float4*)(euid + (size_t)huid[base + 2] * 128 + cu);
              const float4* u3 = (const float4*)(euid + (size_t)huid[base + 3] * 128 + cu);
#define AVG4(idx, dst) { float4 a=u0[idx],b4=u1[idx],c4=u2[idx],d4=u3[idx];            \
        dst.x=0.25f*(a.x+b4.x+c4.x+d4.x); dst.y=0.25f*(a.y+b4.y+c4.y+d4.y);           \
        dst.z=0.25f*(a.z+b4.z+c4.z+d4.z); dst.w=0.25f*(a.w+b4.w+c4.w+d4.w); }
              AVG4(0, f0) AVG4(1, f1) AVG4(2, f2) AVG4(3, f3)
#undef AVG4
            }
          }
          short* arow = Asl + srow * LDR + (shalf << 4);
          *(bf16x8*)(arow)     = pack8(f0, f1);
          *(bf16x8*)(arow + 8) = pack8(f2, f3);
        }
        // ---- stage B (weights) ----
        {
          const float* bp = Bmat + (size_t)(bn + srow) * Kdim + k0 + (shalf << 4);
          float4 f0 = ((const float4*)bp)[0], f1 = ((const float4*)bp)[1];
          float4 f2 = ((const float4*)bp)[2], f3 = ((const float4*)bp)[3];
          short* brow = Bsl + srow * LDR + (shalf << 4);
          *(bf16x8*)(brow)     = pack8(f0, f1);
          *(bf16x8*)(brow + 8) = pack8(f2, f3);
        }
        __syncthreads();
        bf16x8 af[4], bfr[4];
#pragma unroll
        for (int i = 0; i < 4; ++i) {
          af[i]  = *(const bf16x8*)(Asl + ((wr << 6) + (i << 4) + m16) * LDR + (g4 << 3));
          bfr[i] = *(const bf16x8*)(Bsl + ((wc << 6) + (i << 4) + m16) * LDR + (g4 << 3));
        }
#pragma unroll
        for (int i = 0; i < 4; ++i)
#pragma unroll
          for (int j = 0; j < 4; ++j)
            acc[i][j] = __builtin_amdgcn_mfma_f32_16x16x32_bf16(af[i], bfr[j], acc[i][j], 0, 0, 0);
        __syncthreads();
      }
      // ---- epilogue ----
      if (isgx) {
#pragma unroll
        for (int i = 0; i < 4; ++i)
#pragma unroll
          for (int j = 0; j < 4; ++j) {
            const int col = bn + (wc << 6) + (j << 4) + m16;
            const float bv = bias[col];
#pragma unroll
            for (int q = 0; q < 4; ++q) {
              const int row = bm + (wr << 6) + (i << 4) + (g4 << 2) + q;
              gx[(size_t)row * 1536 + col] = acc[i][j][q] + bv;
            }
          }
        asm volatile("s_waitcnt vmcnt(0)" ::: "memory");
        __syncthreads();
        if (tid == 0) {
          // release-add: writes back L2 (tile visible at L3), then bump total
          __hip_atomic_fetch_add(sync + 512 + yt, 1u, __ATOMIC_RELEASE, __HIP_MEMORY_SCOPE_AGENT);
          asm volatile("s_waitcnt vmcnt(0)" ::: "memory");
          __hip_atomic_fetch_add(sync + 576, 1u, __ATOMIC_RELAXED, __HIP_MEMORY_SCOPE_AGENT);
        }
      } else {
#pragma unroll
        for (int i = 0; i < 4; ++i)
#pragma unroll
          for (int j = 0; j < 4; ++j) {
            const int col = bn + (wc << 6) + (j << 4) + m16;
            const float bv = bias[col];
#pragma unroll
            for (int q = 0; q < 4; ++q) {
              const int row = bm + (wr << 6) + (i << 4) + (g4 << 2) + q;
              histt[(size_t)row * 512 + col] = tanhf(acc[i][j][q] + bv);
            }
          }
      }
    }
    return;
  }

  // ================= GRU role: 32 blocks x 4 waves =================
  // bid2 = (gp = group-pair, c = j-chunk). wave w: grp = 2gp + (w>>1), tt = w&1.
  // Weight slabs (96 KB, 32 j-rows) shared by both groups of the pair.
  const int bid2 = bid - (GXB + ATB);
  const int w = tid >> 6, lane = tid & 63;
  const int gp = bid2 & 1, c = bid2 >> 1;
  const int grp = (gp << 1) | (w >> 1), tt = w & 1;
  const int j0 = (c << 5) + (tt << 4);
  const int b0 = grp << 4;
  const int m16 = lane & 15, g4 = lane >> 4;

  if (w < 2) {   // waves 0,1 load the shared slabs (w==tt here)
    for (int gi = 0; gi < 3; ++gi) {
      const float* wg = W_hh + (size_t)(gi * 512 + j0) * 512;
      short* slab = smem + (((gi << 1) + tt) << 13);
      for (int r = 0; r < 16; ++r) {
        const int k = lane << 3;
        const float4* src = (const float4*)(wg + (size_t)r * 512 + k);
        const int off = ((r << 9) + k) ^ ((r & 7) << 3);
        *(bf16x8*)(slab + off) = pack8(src[0], src[1]);
      }
    }
  }
  __syncthreads();

  const int bcol = b0 + m16;
  const int jr = j0 + (g4 << 2);
  const f32x4 bhr = *(const f32x4*)&b_hh[jr];
  const f32x4 bhz = *(const f32x4*)&b_hh[512 + jr];
  const f32x4 bhn = *(const f32x4*)&b_hh[1024 + jr];
  const int lenb = lens[bcol];
  f32x4 hprev = {0.f, 0.f, 0.f, 0.f};

  unsigned int* gflags = sync + (gp << 8);       // 16 flags x 16 dwords
  unsigned int* ownflag = gflags + (c << 4);
  bool all_done = false;

  for (int t = 0; t < 128; ++t) {
    // ---- gate on gx availability for this step ----
    if (!all_done) {
      if (__hip_atomic_load(sync + 576, __ATOMIC_RELAXED, __HIP_MEMORY_SCOPE_AGENT) == 768u)
        all_done = true;
      else {
        const int yt = t >> 1;
        while (__hip_atomic_load(sync + 512 + yt, __ATOMIC_RELAXED, __HIP_MEMORY_SCOPE_AGENT) < 12u) {
          if (__hip_atomic_load(sync + 576, __ATOMIC_RELAXED, __HIP_MEMORY_SCOPE_AGENT) == 768u) {
            all_done = true; break;
          }
        }
      }
      asm volatile("" ::: "memory");
    }
    // gx loads (L3-direct atomics; producers pushed via release-writeback)
    const u64* gxp = (const u64*)(gx + ((size_t)t * 64 + bcol) * 1536 + jr);
    u64 g0 = __hip_atomic_load(gxp,       __ATOMIC_RELAXED, __HIP_MEMORY_SCOPE_AGENT);
    u64 g1 = __hip_atomic_load(gxp + 1,   __ATOMIC_RELAXED, __HIP_MEMORY_SCOPE_AGENT);
    u64 g2 = __hip_atomic_load(gxp + 256, __ATOMIC_RELAXED, __HIP_MEMORY_SCOPE_AGENT);
    u64 g3 = __hip_atomic_load(gxp + 257, __ATOMIC_RELAXED, __HIP_MEMORY_SCOPE_AGENT);
    u64 g4v= __hip_atomic_load(gxp + 512, __ATOMIC_RELAXED, __HIP_MEMORY_SCOPE_AGENT);
    u64 g5 = __hip_atomic_load(gxp + 513, __ATOMIC_RELAXED, __HIP_MEMORY_SCOPE_AGENT);
    u64x2 p0; p0[0] = g0; p0[1] = g1;
    u64x2 p1; p1[0] = g2; p1[1] = g3;
    u64x2 p2; p2[0] = g4v; p2[1] = g5;
    f32x4 gr = __builtin_bit_cast(f32x4, p0);
    f32x4 gz = __builtin_bit_cast(f32x4, p1);
    f32x4 gn = __builtin_bit_cast(f32x4, p2);

    f32x4 ar = {0.f, 0.f, 0.f, 0.f}, az = ar, an = ar;
    if (t) {
      // wait: all 16 chunk-blocks of this group-pair finished step t-1
      const unsigned tgt = (unsigned)t;
      while (true) {
        unsigned f = tgt;
        if (lane < 16)
          f = __hip_atomic_load(gflags + (lane << 4), __ATOMIC_RELAXED, __HIP_MEMORY_SCOPE_AGENT);
        if (__all((int)(f >= tgt))) break;
      }
      asm volatile("" ::: "memory");

      const u64* hp = (const u64*)(h_bf + ((t & 1) << 15) + (size_t)bcol * 512 + (g4 << 3));
      u64 hu[32];
#pragma unroll
      for (int ks = 0; ks < 16; ++ks) {
        hu[2 * ks]     = __hip_atomic_load(hp + ks * 8,     __ATOMIC_RELAXED, __HIP_MEMORY_SCOPE_AGENT);
        hu[2 * ks + 1] = __hip_atomic_load(hp + ks * 8 + 1, __ATOMIC_RELAXED, __HIP_MEMORY_SCOPE_AGENT);
      }
#define GRU_MFMA(ks)                                                                 \
      {                                                                              \
        u64x2 p; p[0] = hu[2 * (ks)]; p[1] = hu[2 * (ks) + 1];                       \
        bf16x8 hf = __builtin_bit_cast(bf16x8, p);                                   \
        int off = ((m16 << 9) + ((ks) << 5) + (g4 << 3)) ^ ((m16 & 7) << 3);         \
        ar = __builtin_amdgcn_mfma_f32_16x16x32_bf16(*(const bf16x8*)(smem + ((0 + tt) << 13) + off), hf, ar, 0, 0, 0); \
        az = __builtin_amdgcn_mfma_f32_16x16x32_bf16(*(const bf16x8*)(smem + ((2 + tt) << 13) + off), hf, az, 0, 0, 0); \
        an = __builtin_amdgcn_mfma_f32_16x16x32_bf16(*(const bf16x8*)(smem + ((4 + tt) << 13) + off), hf, an, 0, 0, 0); \
      }
      GRU_MFMA(0)  GRU_MFMA(1)  GRU_MFMA(2)  GRU_MFMA(3)
      GRU_MFMA(4)  GRU_MFMA(5)  GRU_MFMA(6)  GRU_MFMA(7)
      GRU_MFMA(8)  GRU_MFMA(9)  GRU_MFMA(10) GRU_MFMA(11)
      GRU_MFMA(12) GRU_MFMA(13) GRU_MFMA(14) GRU_MFMA(15)
#undef GRU_MFMA
    }
    u16x4 hw;
#pragma unroll
    for (int q = 0; q < 4; ++q) {
      float r = 1.f / (1.f + __expf(-(gr[q] + ar[q] + bhr[q])));
      float z = 1.f / (1.f + __expf(-(gz[q] + az[q] + bhz[q])));
      float xn = gn[q] + r * (an[q] + bhn[q]);
      float n = 1.f - 2.f / (__expf(2.f * xn) + 1.f);
      float hv = (1.f - z) * n + z * hprev[q];
      hprev[q] = hv;
      hw[q] = f2bf(hv);
    }
    __hip_atomic_store((u64*)(h_bf + ((~t & 1) << 15) + (size_t)bcol * 512 + jr),
                       __builtin_bit_cast(u64, hw),
                       __ATOMIC_RELAXED, __HIP_MEMORY_SCOPE_AGENT);
    if (t == lenb - 1) {
      *(f32x4*)(lastb + (size_t)bcol * 512 + jr) = hprev;
    }
    if (t < 127) {
      asm volatile("s_waitcnt vmcnt(0)" ::: "memory");   // h stores acked at L3
      __syncthreads();                                   // join all 4 waves
      if (tid == 0)
        __hip_atomic_store(ownflag, (unsigned)(t + 1), __ATOMIC_RELAXED, __HIP_MEMORY_SCOPE_AGENT);
    }
  }
}

// ---------------- attention: energies, softmax, context (one block per b) ----------------
__global__ __launch_bounds__(256)
void attn_ctx(const float* __restrict__ histt, const float* __restrict__ last,
              float* __restrict__ ctx) {
  int b = blockIdx.x, tid = threadIdx.x;
  __shared__ float ls[512];
  __shared__ float w[256];
  __shared__ float red[256];
  ((float2*)ls)[tid] = ((const float2*)(last + (size_t)b * 512))[tid];
  __syncthreads();
  const float* hb = histt + (size_t)b * 256 * 512;
  const float* hrow = hb + (size_t)tid * 512;
  float acc = 0.f;
  for (int k = 0; k < 512; k += 4) {
    float4 h4 = *(const float4*)(hrow + k);
    acc += ls[k] * h4.x + ls[k + 1] * h4.y + ls[k + 2] * h4.z + ls[k + 3] * h4.w;
  }
  red[tid] = acc;
  __syncthreads();
  for (int s = 128; s; s >>= 1) {
    if (tid < s) red[tid] = fmaxf(red[tid], red[tid + s]);
    __syncthreads();
  }
  float m = red[0];
  __syncthreads();
  float ex = expf(acc - m);
  w[tid] = ex; red[tid] = ex;
  __syncthreads();
  for (int s = 128; s; s >>= 1) {
    if (tid < s) red[tid] += red[tid + s];
    __syncthreads();
  }
  float inv = 1.f / red[0];
  float c0 = 0.f, c1 = 0.f;
  for (int n = 0; n < 256; ++n) {
    float wn = w[n];
    c0 += wn * hb[(size_t)n * 512 + tid];
    c1 += wn * hb[(size_t)n * 512 + tid + 256];
  }
  ctx[(size_t)b * 512 + tid]       = c0 * inv;
  ctx[(size_t)b * 512 + tid + 256] = c1 * inv;
}

// ---------------- final: y[b][u] = [last|ctx|last] . W_final[u] + b_final[u] ----------------
__global__ __launch_bounds__(256)
void final_gemm(const float* __restrict__ last, const float* __restrict__ ctx,
                const float* __restrict__ Wf, const float* __restrict__ bf,
                float* __restrict__ y) {
  __shared__ float s[64][129];
  const int tid = threadIdx.x;
  const int u0 = blockIdx.x << 3;
  const int ul = tid >> 6, b = tid & 63;
  float acc0 = 0.f, acc1 = 0.f;
  for (int kc = 0; kc < 12; ++kc) {
    __syncthreads();
    for (int i = tid; i < 2048; i += 256) {
      int rb = i >> 5, cc = (i & 31) << 2;
      int k = kc * 128 + cc;
      const float* src = (k < 512) ? (last + (size_t)rb * 512 + k)
                       : (k < 1024) ? (ctx + (size_t)rb * 512 + k - 512)
                                    : (last + (size_t)rb * 512 + k - 1024);
      float4 v = *(const float4*)src;
      s[rb][cc] = v.x; s[rb][cc + 1] = v.y; s[rb][cc + 2] = v.z; s[rb][cc + 3] = v.w;
    }
    __syncthreads();
#pragma unroll
    for (int uu = 0; uu < 2; ++uu) {
      int u = u0 + ul + uu * 4;
      const float* wrow = Wf + (size_t)u * 1536 + kc * 128;
      float a = 0.f;
#pragma unroll 8
      for (int c = 0; c < 128; c += 4) {
        float4 w4 = *(const float4*)(wrow + c);
        a += w4.x * s[b][c] + w4.y * s[b][c + 1] + w4.z * s[b][c + 2] + w4.w * s[b][c + 3];
      }
      if (uu == 0) acc0 += a; else acc1 += a;
    }
  }
  int u = u0 + ul;
  y[(size_t)b * 5000 + u]     = acc0 + bf[u];
  y[(size_t)b * 5000 + u + 4] = acc1 + bf[u + 4];
}

// ---------------- broadcast y (B,5000) -> out (B,T,5000) ----------------
__global__ void broadcast_y(const float* __restrict__ y, float* __restrict__ out) {
  int bt = blockIdx.x;
  const float4* src = (const float4*)(y + (size_t)(bt >> 7) * 5000);
  float4* dst = (float4*)(out + (size_t)bt * 5000);
  for (int i = threadIdx.x; i < 1250; i += 256) dst[i] = src[i];
}

extern "C" void kernel_launch(void* const* d_in, const int* in_sizes, int n_in,
                              void* d_out, int out_size, void* d_ws, size_t ws_size,
                              hipStream_t stream) {
  const int* loc  = (const int*)d_in[0];
  const int* tim  = (const int*)d_in[1];
  const int* lens = (const int*)d_in[2];
  const int* hloc = (const int*)d_in[3];
  const int* htim = (const int*)d_in[4];
  const int* huid = (const int*)d_in[5];
  // d_in[6] = group_size (constant 4, baked in)
  const float* eloc    = (const float*)d_in[7];
  const float* etim    = (const float*)d_in[8];
  const float* euid    = (const float*)d_in[9];
  const float* W_attn  = (const float*)d_in[10];
  const float* b_attn  = (const float*)d_in[11];
  const float* W_ih    = (const float*)d_in[12];
  const float* b_ih    = (const float*)d_in[13];
  const float* W_hh    = (const float*)d_in[14];
  const float* b_hh    = (const float*)d_in[15];
  const float* W_final = (const float*)d_in[16];
  const float* b_final = (const float*)d_in[17];
  float* out = (float*)d_out;
  char* ws = (char*)d_ws;

  // workspace layout (bytes)
  float* gx    = (float*)(ws + 0ull);            // 8192*1536*4 = 50,331,648
  float* histt = (float*)(ws + 50331648ull);     // 16384*512*4 = 33,554,432
  float* lastb = (float*)(ws + 83886080ull);     // 64*512*4 = 131,072
  float* ctx   = (float*)(ws + 84017152ull);     // 131,072
  float* yv    = (float*)(ws + 84148224ull);     // 64*5000*4 = 1,280,000
  short* h_bf  = (short*)(ws + 85428224ull);     // 2*64*512*2 = 131,072
  unsigned int* sync = (unsigned int*)(ws + 85559296ull);  // 4 KB

  hipMemsetAsync(sync, 0, 4096, stream);
  phase1<<<GXB + ATB + GRUB, 256, 0, stream>>>(
      loc, tim, lens, hloc, htim, huid, eloc, etim, euid,
      W_attn, b_attn, W_ih, b_ih, W_hh, b_hh,
      gx, histt, h_bf, lastb, sync);

  attn_ctx<<<64, 256, 0, stream>>>(histt, lastb, ctx);
  final_gemm<<<625, 256, 0, stream>>>(lastb, ctx, W_final, b_final, yv);
  broadcast_y<<<8192, 256, 0, stream>>>(yv, out);
}

// Round 9
// 851.528 us; speedup vs baseline: 1.1048x; 1.1048x over previous
//
#include <hip/hip_runtime.h>
#include <hip/hip_bf16.h>

// Sizes (fixed): B=64 T=128 HID=512 LOC_EMB=256 TIM_EMB=64 UID_EMB=128
// L_HIST=1024 G=4, K_x=320, K_attn=448, N_gates=1536, UID_SIZE=5000

typedef __attribute__((ext_vector_type(8))) short bf16x8;
typedef __attribute__((ext_vector_type(4))) float f32x4;
typedef __attribute__((ext_vector_type(4))) unsigned short u16x4;
typedef __attribute__((ext_vector_type(2))) unsigned long long u64x2;
typedef unsigned long long u64;

__device__ inline unsigned short f2bf(float x) {
  __hip_bfloat16 b = __float2bfloat16(x);
  return __builtin_bit_cast(unsigned short, b);
}

// ---------------- prep: gather_x (blocks 0..8191) + hist_feat (blocks 8192..24575) ----------------
__global__ void prep(const int* __restrict__ loc, const int* __restrict__ tim,
                     const int* __restrict__ hloc, const int* __restrict__ htim,
                     const int* __restrict__ huid,
                     const float* __restrict__ eloc, const float* __restrict__ etim,
                     const float* __restrict__ euid,
                     float* __restrict__ X, float* __restrict__ histf) {
  int bid = blockIdx.x, tid = threadIdx.x;
  if (bid < 8192) {
    int t = bid >> 6, b = bid & 63;
    float4* dst = (float4*)(X + (size_t)bid * 320);
    int li = loc[b * 128 + t];
    dst[tid] = ((const float4*)(eloc + (size_t)li * 256))[tid];
    if (tid < 16) {
      int ti = tim[b * 128 + t];
      dst[64 + tid] = ((const float4*)(etim + (size_t)ti * 64))[tid];
    }
  } else {
    int row = bid - 8192;            // b*256 + n
    int b = row >> 8, n = row & 255;
    int base = b * 1024 + (n << 2);
    float4* dst = (float4*)(histf + (size_t)row * 448);
    {
      int li = hloc[base];
      dst[tid] = ((const float4*)(eloc + (size_t)li * 256))[tid];
    }
    if (tid < 16) {
      int ti = htim[base];
      dst[64 + tid] = ((const float4*)(etim + (size_t)ti * 64))[tid];
    }
    if (tid < 32) {
      const float4* u0 = (const float4*)(euid + (size_t)huid[base + 0] * 128);
      const float4* u1 = (const float4*)(euid + (size_t)huid[base + 1] * 128);
      const float4* u2 = (const float4*)(euid + (size_t)huid[base + 2] * 128);
      const float4* u3 = (const float4*)(euid + (size_t)huid[base + 3] * 128);
      float4 v0 = u0[tid], v1 = u1[tid], v2 = u2[tid], v3 = u3[tid];
      float4 o;
      o.x = 0.25f * (v0.x + v1.x + v2.x + v3.x);
      o.y = 0.25f * (v0.y + v1.y + v2.y + v3.y);
      o.z = 0.25f * (v0.z + v1.z + v2.z + v3.z);
      o.w = 0.25f * (v0.w + v1.w + v2.w + v3.w);
      dst[80 + tid] = o;
    }
  }
}

// ---------------- bf16 MFMA GEMM: C[m][n] = act(sum_k A[m][k]*B[n][k] + bias[n]) ----------------
// BM=BN=128, BK=32, 256 threads = 4 waves (2x2), 64x64 per wave.
// fp32 inputs -> bf16 reg-staged into PADDED LDS rows (stride 40 shorts; 2-way aliasing max).
template<bool TANH>
__global__ __launch_bounds__(256)
void gemm_bf16(const float* __restrict__ A, const float* __restrict__ Bm,
               const float* __restrict__ bias, float* __restrict__ C,
               int M, int N, int K) {
  constexpr int LDR = 40;
  __shared__ short Asl[128 * LDR];
  __shared__ short Bsl[128 * LDR];
  const int tid = threadIdx.x;
  const int lane = tid & 63, wid = tid >> 6;
  const int wr = wid >> 1, wc = wid & 1;
  const int m16 = lane & 15, g4 = lane >> 4;
  const int bm = blockIdx.y * 128, bn = blockIdx.x * 128;
  const int srow = tid >> 1, shalf = tid & 1;
  f32x4 acc[4][4] = {};
  for (int k0 = 0; k0 < K; k0 += 32) {
    {
      const float* ap = A + (size_t)(bm + srow) * K + k0 + (shalf << 4);
      float4 f0 = ((const float4*)ap)[0], f1 = ((const float4*)ap)[1];
      float4 f2 = ((const float4*)ap)[2], f3 = ((const float4*)ap)[3];
      bf16x8 w0, w1;
      w0[0]=(short)f2bf(f0.x); w0[1]=(short)f2bf(f0.y); w0[2]=(short)f2bf(f0.z); w0[3]=(short)f2bf(f0.w);
      w0[4]=(short)f2bf(f1.x); w0[5]=(short)f2bf(f1.y); w0[6]=(short)f2bf(f1.z); w0[7]=(short)f2bf(f1.w);
      w1[0]=(short)f2bf(f2.x); w1[1]=(short)f2bf(f2.y); w1[2]=(short)f2bf(f2.z); w1[3]=(short)f2bf(f2.w);
      w1[4]=(short)f2bf(f3.x); w1[5]=(short)f2bf(f3.y); w1[6]=(short)f2bf(f3.z); w1[7]=(short)f2bf(f3.w);
      short* arow = Asl + srow * LDR + (shalf << 4);
      *(bf16x8*)(arow)     = w0;
      *(bf16x8*)(arow + 8) = w1;
      const float* bp = Bm + (size_t)(bn + srow) * K + k0 + (shalf << 4);
      f0 = ((const float4*)bp)[0]; f1 = ((const float4*)bp)[1];
      f2 = ((const float4*)bp)[2]; f3 = ((const float4*)bp)[3];
      w0[0]=(short)f2bf(f0.x); w0[1]=(short)f2bf(f0.y); w0[2]=(short)f2bf(f0.z); w0[3]=(short)f2bf(f0.w);
      w0[4]=(short)f2bf(f1.x); w0[5]=(short)f2bf(f1.y); w0[6]=(short)f2bf(f1.z); w0[7]=(short)f2bf(f1.w);
      w1[0]=(short)f2bf(f2.x); w1[1]=(short)f2bf(f2.y); w1[2]=(short)f2bf(f2.z); w1[3]=(short)f2bf(f2.w);
      w1[4]=(short)f2bf(f3.x); w1[5]=(short)f2bf(f3.y); w1[6]=(short)f2bf(f3.z); w1[7]=(short)f2bf(f3.w);
      short* brow = Bsl + srow * LDR + (shalf << 4);
      *(bf16x8*)(brow)     = w0;
      *(bf16x8*)(brow + 8) = w1;
    }
    __syncthreads();
    bf16x8 af[4], bfr[4];
#pragma unroll
    for (int i = 0; i < 4; ++i) {
      af[i]  = *(const bf16x8*)(Asl + ((wr << 6) + (i << 4) + m16) * LDR + (g4 << 3));
      bfr[i] = *(const bf16x8*)(Bsl + ((wc << 6) + (i << 4) + m16) * LDR + (g4 << 3));
    }
#pragma unroll
    for (int i = 0; i < 4; ++i)
#pragma unroll
      for (int j = 0; j < 4; ++j)
        acc[i][j] = __builtin_amdgcn_mfma_f32_16x16x32_bf16(af[i], bfr[j], acc[i][j], 0, 0, 0);
    __syncthreads();
  }
#pragma unroll
  for (int i = 0; i < 4; ++i) {
#pragma unroll
    for (int j = 0; j < 4; ++j) {
      int col = bn + (wc << 6) + (j << 4) + m16;
      float bv = bias[col];
#pragma unroll
      for (int q = 0; q < 4; ++q) {
        int row = bm + (wr << 6) + (i << 4) + (g4 << 2) + q;
        float v = acc[i][j][q] + bv;
        if (TANH) v = tanhf(v);
        C[(size_t)row * N + col] = v;
      }
    }
  }
}

// ---------------- persistent GRU: sentinel-dataflow, no flags/fences/barriers ----------------
// 64 blocks x 128 threads (2 independent waves after init).
// block = (chunk c = bid>>2 in [0,16), group g = bid&3); wave tt owns 16 j-rows
// [32c+16tt, +16) for batches [16g, 16g+16). Weights in LDS (96 KB, XOR-swizzled).
// h exchange: per-step buffer h_all[t] (bf16, pre-memset 0xFF = NaN sentinel).
//   producer: one relaxed 8B atomic store per lane. consumer: relaxed 8B atomic
//   loads, retrying units whose low short == 0xFFFF (real h is finite => never NaN).
// Data arrival IS the signal: 8B atomicity => one-short check validates the unit.
__global__ __launch_bounds__(128)
void gru_persist(const float* __restrict__ gx, const float* __restrict__ W_hh,
                 const float* __restrict__ b_hh, const int* __restrict__ lens,
                 short* __restrict__ h_all, float* __restrict__ lastb) {
  __shared__ short wlds[6 * 16 * 512];   // 6 slabs (3 gates x 2 waves) x 16x512 bf16 = 96 KB
  const int tid = threadIdx.x;
  const int lane = tid & 63, tt = tid >> 6;
  const int bid = blockIdx.x;
  const int c = bid >> 2, grp = bid & 3;
  const int j0 = (c << 5) + (tt << 4);   // this wave's 16 j-rows
  const int b0 = grp << 4;               // 16 batches
  const int m16 = lane & 15, g4 = lane >> 4;

  // ---- load this wave's weight slabs into LDS (once), fp32 -> bf16, swizzled ----
  for (int gi = 0; gi < 3; ++gi) {
    const float* wg = W_hh + (size_t)(gi * 512 + j0) * 512;
    short* slab = wlds + (((gi << 1) + tt) << 13);
    for (int r = 0; r < 16; ++r) {
      int k = lane << 3;
      const float4* src = (const float4*)(wg + (size_t)r * 512 + k);
      float4 f0 = src[0], f1 = src[1];
      bf16x8 w;
      w[0]=(short)f2bf(f0.x); w[1]=(short)f2bf(f0.y); w[2]=(short)f2bf(f0.z); w[3]=(short)f2bf(f0.w);
      w[4]=(short)f2bf(f1.x); w[5]=(short)f2bf(f1.y); w[6]=(short)f2bf(f1.z); w[7]=(short)f2bf(f1.w);
      int off = ((r << 9) + k) ^ ((r & 7) << 3);   // short units (row=512 shorts, safe XOR)
      *(bf16x8*)(slab + off) = w;
    }
  }

  // ---- per-lane constants ----
  const int bcol = b0 + m16;             // this lane's batch (C-col)
  const int jr = j0 + (g4 << 2);         // this lane's 4 output j-rows (C-rows)
  const f32x4 bhr = *(const f32x4*)&b_hh[jr];
  const f32x4 bhz = *(const f32x4*)&b_hh[512 + jr];
  const f32x4 bhn = *(const f32x4*)&b_hh[1024 + jr];
  const int lenb = lens[bcol];
  int tmax = 0;                          // group-uniform early exit
  for (int i = 0; i < 16; ++i) tmax = max(tmax, lens[b0 + i]);
  f32x4 hprev = {0.f, 0.f, 0.f, 0.f};

  for (int t = 0; t < tmax; ++t) {
    // gx loads first: independent of h, latency hides under the data poll
    const float* gxb = gx + ((size_t)t * 64 + bcol) * 1536;
    f32x4 gr = *(const f32x4*)(gxb + jr);
    f32x4 gz = *(const f32x4*)(gxb + 512 + jr);
    f32x4 gn = *(const f32x4*)(gxb + 1024 + jr);
    f32x4 ar = {0.f, 0.f, 0.f, 0.f}, az = ar, an = ar;
    if (t) {
      // consume h(t-1): retry units still holding the 0xFFFF sentinel
      const u64* hp = (const u64*)(h_all + (size_t)(t - 1) * 32768 + (size_t)bcol * 512 + (g4 << 3));
      u64 hu[32];
      unsigned miss = 0xFFFFFFFFu;
      while (miss) {
        unsigned nm = 0;
#pragma unroll
        for (int k2 = 0; k2 < 32; ++k2) {
          if (miss & (1u << k2))
            hu[k2] = __hip_atomic_load(hp + ((k2 >> 1) << 3) + (k2 & 1),
                                       __ATOMIC_RELAXED, __HIP_MEMORY_SCOPE_AGENT);
        }
#pragma unroll
        for (int k2 = 0; k2 < 32; ++k2)
          if ((unsigned short)(hu[k2] & 0xFFFFu) == 0xFFFFu) nm |= (1u << k2);
        miss = nm;
      }
#define GRU_MFMA(ks)                                                                 \
      {                                                                              \
        u64x2 p; p[0] = hu[2 * (ks)]; p[1] = hu[2 * (ks) + 1];                       \
        bf16x8 hf = __builtin_bit_cast(bf16x8, p);                                   \
        int off = ((m16 << 9) + ((ks) << 5) + (g4 << 3)) ^ ((m16 & 7) << 3);         \
        ar = __builtin_amdgcn_mfma_f32_16x16x32_bf16(*(const bf16x8*)(wlds + ((0 + tt) << 13) + off), hf, ar, 0, 0, 0); \
        az = __builtin_amdgcn_mfma_f32_16x16x32_bf16(*(const bf16x8*)(wlds + ((2 + tt) << 13) + off), hf, az, 0, 0, 0); \
        an = __builtin_amdgcn_mfma_f32_16x16x32_bf16(*(const bf16x8*)(wlds + ((4 + tt) << 13) + off), hf, an, 0, 0, 0); \
      }
      GRU_MFMA(0)  GRU_MFMA(1)  GRU_MFMA(2)  GRU_MFMA(3)
      GRU_MFMA(4)  GRU_MFMA(5)  GRU_MFMA(6)  GRU_MFMA(7)
      GRU_MFMA(8)  GRU_MFMA(9)  GRU_MFMA(10) GRU_MFMA(11)
      GRU_MFMA(12) GRU_MFMA(13) GRU_MFMA(14) GRU_MFMA(15)
#undef GRU_MFMA
    }
    u16x4 hw;
#pragma unroll
    for (int q = 0; q < 4; ++q) {
      float r = 1.f / (1.f + __expf(-(gr[q] + ar[q] + bhr[q])));
      float z = 1.f / (1.f + __expf(-(gz[q] + az[q] + bhz[q])));
      float xn = gn[q] + r * (an[q] + bhn[q]);
      float n = 1.f - 2.f / (__expf(2.f * xn) + 1.f);
      float hv = (1.f - z) * n + z * hprev[q];
      hprev[q] = hv;
      hw[q] = f2bf(hv);
    }
    // produce h(t): single relaxed atomic store; arrival is the signal
    __hip_atomic_store((u64*)(h_all + (size_t)t * 32768 + (size_t)bcol * 512 + jr),
                       __builtin_bit_cast(u64, hw),
                       __ATOMIC_RELAXED, __HIP_MEMORY_SCOPE_AGENT);
    if (t == lenb - 1) {
      *(f32x4*)(lastb + (size_t)bcol * 512 + jr) = hprev;
    }
  }
}

// ---------------- attention: energies, softmax, context (one block per b) ----------------
__global__ __launch_bounds__(256)
void attn_ctx(const float* __restrict__ histt, const float* __restrict__ last,
              float* __restrict__ ctx) {
  int b = blockIdx.x, tid = threadIdx.x;
  __shared__ float ls[512];
  __shared__ float w[256];
  __shared__ float red[256];
  ((float2*)ls)[tid] = ((const float2*)(last + (size_t)b * 512))[tid];
  __syncthreads();
  const float* hb = histt + (size_t)b * 256 * 512;
  const float* hrow = hb + (size_t)tid * 512;
  float acc = 0.f;
  for (int k = 0; k < 512; k += 4) {
    float4 h4 = *(const float4*)(hrow + k);
    acc += ls[k] * h4.x + ls[k + 1] * h4.y + ls[k + 2] * h4.z + ls[k + 3] * h4.w;
  }
  red[tid] = acc;
  __syncthreads();
  for (int s = 128; s; s >>= 1) {
    if (tid < s) red[tid] = fmaxf(red[tid], red[tid + s]);
    __syncthreads();
  }
  float m = red[0];
  __syncthreads();
  float ex = expf(acc - m);
  w[tid] = ex; red[tid] = ex;
  __syncthreads();
  for (int s = 128; s; s >>= 1) {
    if (tid < s) red[tid] += red[tid + s];
    __syncthreads();
  }
  float inv = 1.f / red[0];
  float c0 = 0.f, c1 = 0.f;
  for (int n = 0; n < 256; ++n) {
    float wn = w[n];
    c0 += wn * hb[(size_t)n * 512 + tid];
    c1 += wn * hb[(size_t)n * 512 + tid + 256];
  }
  ctx[(size_t)b * 512 + tid]       = c0 * inv;
  ctx[(size_t)b * 512 + tid + 256] = c1 * inv;
}

// ---------------- final: y[b][u] = [last|ctx|last] . W_final[u] + b_final[u] ----------------
__global__ __launch_bounds__(256)
void final_gemm(const float* __restrict__ last, const float* __restrict__ ctx,
                const float* __restrict__ Wf, const float* __restrict__ bf,
                float* __restrict__ y) {
  __shared__ float s[64][129];
  const int tid = threadIdx.x;
  const int u0 = blockIdx.x << 3;
  const int ul = tid >> 6, b = tid & 63;
  float acc0 = 0.f, acc1 = 0.f;
  for (int kc = 0; kc < 12; ++kc) {
    __syncthreads();
    for (int i = tid; i < 2048; i += 256) {
      int rb = i >> 5, cc = (i & 31) << 2;
      int k = kc * 128 + cc;
      const float* src = (k < 512) ? (last + (size_t)rb * 512 + k)
                       : (k < 1024) ? (ctx + (size_t)rb * 512 + k - 512)
                                    : (last + (size_t)rb * 512 + k - 1024);
      float4 v = *(const float4*)src;
      s[rb][cc] = v.x; s[rb][cc + 1] = v.y; s[rb][cc + 2] = v.z; s[rb][cc + 3] = v.w;
    }
    __syncthreads();
#pragma unroll
    for (int uu = 0; uu < 2; ++uu) {
      int u = u0 + ul + uu * 4;
      const float* wrow = Wf + (size_t)u * 1536 + kc * 128;
      float a = 0.f;
#pragma unroll 8
      for (int c = 0; c < 128; c += 4) {
        float4 w4 = *(const float4*)(wrow + c);
        a += w4.x * s[b][c] + w4.y * s[b][c + 1] + w4.z * s[b][c + 2] + w4.w * s[b][c + 3];
      }
      if (uu == 0) acc0 += a; else acc1 += a;
    }
  }
  int u = u0 + ul;
  y[(size_t)b * 5000 + u]     = acc0 + bf[u];
  y[(size_t)b * 5000 + u + 4] = acc1 + bf[u + 4];
}

// ---------------- broadcast y (B,5000) -> out (B,T,5000) ----------------
__global__ void broadcast_y(const float* __restrict__ y, float* __restrict__ out) {
  int bt = blockIdx.x;
  const float4* src = (const float4*)(y + (size_t)(bt >> 7) * 5000);
  float4* dst = (float4*)(out + (size_t)bt * 5000);
  for (int i = threadIdx.x; i < 1250; i += 256) dst[i] = src[i];
}

extern "C" void kernel_launch(void* const* d_in, const int* in_sizes, int n_in,
                              void* d_out, int out_size, void* d_ws, size_t ws_size,
                              hipStream_t stream) {
  const int* loc  = (const int*)d_in[0];
  const int* tim  = (const int*)d_in[1];
  const int* lens = (const int*)d_in[2];
  const int* hloc = (const int*)d_in[3];
  const int* htim = (const int*)d_in[4];
  const int* huid = (const int*)d_in[5];
  // d_in[6] = group_size (constant 4, baked in)
  const float* eloc    = (const float*)d_in[7];
  const float* etim    = (const float*)d_in[8];
  const float* euid    = (const float*)d_in[9];
  const float* W_attn  = (const float*)d_in[10];
  const float* b_attn  = (const float*)d_in[11];
  const float* W_ih    = (const float*)d_in[12];
  const float* b_ih    = (const float*)d_in[13];
  const float* W_hh    = (const float*)d_in[14];
  const float* b_hh    = (const float*)d_in[15];
  const float* W_final = (const float*)d_in[16];
  const float* b_final = (const float*)d_in[17];
  float* out = (float*)d_out;
  char* ws = (char*)d_ws;

  // workspace layout (bytes); h_all aliases histf (dead after gemm_attn; memset after it)
  float* gx    = (float*)(ws + 0ull);            // 8192*1536*4 = 50,331,648
  float* X     = (float*)(ws + 50331648ull);     // 8192*320*4  = 10,485,760
  float* histf = (float*)(ws + 60817408ull);     // 16384*448*4 = 29,360,128
  short* h_all = (short*)(ws + 60817408ull);     // 128*64*512*2 = 8,388,608 (aliases histf)
  float* histt = (float*)(ws + 90177536ull);     // 16384*512*4 = 33,554,432
  float* lastb = (float*)(ws + 123731968ull);    // 64*512*4
  float* ctx   = (float*)(ws + 123863040ull);    // 64*512*4
  float* yv    = (float*)(ws + 123994112ull);    // 64*5000*4 = 1,280,000 (end ~125.3 MB)

  prep<<<24576, 64, 0, stream>>>(loc, tim, hloc, htim, huid, eloc, etim, euid, X, histf);
  gemm_bf16<false><<<dim3(12, 64), 256, 0, stream>>>(X, W_ih, b_ih, gx, 8192, 1536, 320);
  gemm_bf16<true><<<dim3(4, 128), 256, 0, stream>>>(histf, W_attn, b_attn, histt, 16384, 512, 448);

  // sentinel-fill the per-step h buffers (histf is dead now)
  hipMemsetAsync(h_all, 0xFF, 128 * 64 * 512 * sizeof(short), stream);
  gru_persist<<<64, 128, 0, stream>>>(gx, W_hh, b_hh, lens, h_all, lastb);

  attn_ctx<<<64, 256, 0, stream>>>(histt, lastb, ctx);
  final_gemm<<<625, 256, 0, stream>>>(lastb, ctx, W_final, b_final, yv);
  broadcast_y<<<8192, 256, 0, stream>>>(yv, out);
}

// Round 10
// 685.556 us; speedup vs baseline: 1.3722x; 1.2421x over previous
//
#include <hip/hip_runtime.h>
#include <hip/hip_bf16.h>

// Sizes (fixed): B=64 T=128 HID=512 LOC_EMB=256 TIM_EMB=64 UID_EMB=128
// L_HIST=1024 G=4, K_x=320, K_attn=448, N_gates=1536, UID_SIZE=5000

typedef __attribute__((ext_vector_type(8))) short bf16x8;
typedef __attribute__((ext_vector_type(4))) float f32x4;
typedef __attribute__((ext_vector_type(4))) unsigned short u16x4;
typedef __attribute__((ext_vector_type(2))) unsigned long long u64x2;
typedef unsigned long long u64;

__device__ inline unsigned short f2bf(float x) {
  __hip_bfloat16 b = __float2bfloat16(x);
  return __builtin_bit_cast(unsigned short, b);
}
__device__ inline bf16x8 pack8(float4 a, float4 b) {
  bf16x8 w;
  w[0]=(short)f2bf(a.x); w[1]=(short)f2bf(a.y); w[2]=(short)f2bf(a.z); w[3]=(short)f2bf(a.w);
  w[4]=(short)f2bf(b.x); w[5]=(short)f2bf(b.y); w[6]=(short)f2bf(b.z); w[7]=(short)f2bf(b.w);
  return w;
}

// ---------------- gather-fused bf16 GEMM: gx = [emb_loc|emb_tim] @ W_ih^T + b_ih ----------------
// grid (12, 64): 128x128 tile, BK=32, 4 waves, padded LDS (stride 40 shorts).
__global__ __launch_bounds__(256)
void gemm_gx_f(const int* __restrict__ loc, const int* __restrict__ tim,
               const float* __restrict__ eloc, const float* __restrict__ etim,
               const float* __restrict__ W_ih, const float* __restrict__ b_ih,
               float* __restrict__ gx) {
  constexpr int LDR = 40, K = 320, N = 1536;
  __shared__ short Asl[128 * LDR];
  __shared__ short Bsl[128 * LDR];
  const int tid = threadIdx.x;
  const int lane = tid & 63, wid = tid >> 6;
  const int wr = wid >> 1, wc = wid & 1;
  const int m16 = lane & 15, g4 = lane >> 4;
  const int bm = blockIdx.y * 128, bn = blockIdx.x * 128;
  const int srow = tid >> 1, shalf = tid & 1;
  f32x4 acc[4][4] = {};
  for (int k0 = 0; k0 < K; k0 += 32) {
    {
      const int grow = bm + srow;
      const int t = grow >> 6, b = grow & 63;
      const float* ap = (k0 < 256)
        ? eloc + (size_t)loc[b * 128 + t] * 256 + k0 + (shalf << 4)
        : etim + (size_t)tim[b * 128 + t] * 64 + (k0 - 256) + (shalf << 4);
      float4 f0 = ((const float4*)ap)[0], f1 = ((const float4*)ap)[1];
      float4 f2 = ((const float4*)ap)[2], f3 = ((const float4*)ap)[3];
      short* arow = Asl + srow * LDR + (shalf << 4);
      *(bf16x8*)(arow)     = pack8(f0, f1);
      *(bf16x8*)(arow + 8) = pack8(f2, f3);
      const float* bp = W_ih + (size_t)(bn + srow) * K + k0 + (shalf << 4);
      f0 = ((const float4*)bp)[0]; f1 = ((const float4*)bp)[1];
      f2 = ((const float4*)bp)[2]; f3 = ((const float4*)bp)[3];
      short* brow = Bsl + srow * LDR + (shalf << 4);
      *(bf16x8*)(brow)     = pack8(f0, f1);
      *(bf16x8*)(brow + 8) = pack8(f2, f3);
    }
    __syncthreads();
    bf16x8 af[4], bfr[4];
#pragma unroll
    for (int i = 0; i < 4; ++i) {
      af[i]  = *(const bf16x8*)(Asl + ((wr << 6) + (i << 4) + m16) * LDR + (g4 << 3));
      bfr[i] = *(const bf16x8*)(Bsl + ((wc << 6) + (i << 4) + m16) * LDR + (g4 << 3));
    }
#pragma unroll
    for (int i = 0; i < 4; ++i)
#pragma unroll
      for (int j = 0; j < 4; ++j)
        acc[i][j] = __builtin_amdgcn_mfma_f32_16x16x32_bf16(af[i], bfr[j], acc[i][j], 0, 0, 0);
    __syncthreads();
  }
#pragma unroll
  for (int i = 0; i < 4; ++i)
#pragma unroll
    for (int j = 0; j < 4; ++j) {
      const int col = bn + (wc << 6) + (j << 4) + m16;
      const float bv = b_ih[col];
#pragma unroll
      for (int q = 0; q < 4; ++q) {
        const int row = bm + (wr << 6) + (i << 4) + (g4 << 2) + q;
        gx[(size_t)row * N + col] = acc[i][j][q] + bv;
      }
    }
}

// ---------------- gather-fused bf16 GEMM: histt = tanh(hist @ W_attn^T + b_attn) ----------------
// grid (4, 128). hist row = [eloc[hloc] | etim[htim] | mean4(euid[huid])], K=448.
__global__ __launch_bounds__(256)
void gemm_attn_f(const int* __restrict__ hloc, const int* __restrict__ htim,
                 const int* __restrict__ huid,
                 const float* __restrict__ eloc, const float* __restrict__ etim,
                 const float* __restrict__ euid,
                 const float* __restrict__ W_attn, const float* __restrict__ b_attn,
                 float* __restrict__ histt) {
  constexpr int LDR = 40, K = 448, N = 512;
  __shared__ short Asl[128 * LDR];
  __shared__ short Bsl[128 * LDR];
  const int tid = threadIdx.x;
  const int lane = tid & 63, wid = tid >> 6;
  const int wr = wid >> 1, wc = wid & 1;
  const int m16 = lane & 15, g4 = lane >> 4;
  const int bm = blockIdx.y * 128, bn = blockIdx.x * 128;
  const int srow = tid >> 1, shalf = tid & 1;
  f32x4 acc[4][4] = {};
  for (int k0 = 0; k0 < K; k0 += 32) {
    {
      const int grow = bm + srow;
      const int b = grow >> 8, n = grow & 255;
      const int base = b * 1024 + (n << 2);
      float4 f0, f1, f2, f3;
      if (k0 < 256) {
        const float* ap = eloc + (size_t)hloc[base] * 256 + k0 + (shalf << 4);
        f0 = ((const float4*)ap)[0]; f1 = ((const float4*)ap)[1];
        f2 = ((const float4*)ap)[2]; f3 = ((const float4*)ap)[3];
      } else if (k0 < 320) {
        const float* ap = etim + (size_t)htim[base] * 64 + (k0 - 256) + (shalf << 4);
        f0 = ((const float4*)ap)[0]; f1 = ((const float4*)ap)[1];
        f2 = ((const float4*)ap)[2]; f3 = ((const float4*)ap)[3];
      } else {
        const int cu = (k0 - 320) + (shalf << 4);
        const float4* u0 = (const float4*)(euid + (size_t)huid[base + 0] * 128 + cu);
        const float4* u1 = (const float4*)(euid + (size_t)huid[base + 1] * 128 + cu);
        const float4* u2 = (const float4*)(euid + (size_t)huid[base + 2] * 128 + cu);
        const float4* u3 = (const float4*)(euid + (size_t)huid[base + 3] * 128 + cu);
#define AVG4(idx, dst) { float4 a=u0[idx],b4=u1[idx],c4=u2[idx],d4=u3[idx];            \
        dst.x=0.25f*(a.x+b4.x+c4.x+d4.x); dst.y=0.25f*(a.y+b4.y+c4.y+d4.y);           \
        dst.z=0.25f*(a.z+b4.z+c4.z+d4.z); dst.w=0.25f*(a.w+b4.w+c4.w+d4.w); }
        AVG4(0, f0) AVG4(1, f1) AVG4(2, f2) AVG4(3, f3)
#undef AVG4
      }
      short* arow = Asl + srow * LDR + (shalf << 4);
      *(bf16x8*)(arow)     = pack8(f0, f1);
      *(bf16x8*)(arow + 8) = pack8(f2, f3);
      const float* bp = W_attn + (size_t)(bn + srow) * K + k0 + (shalf << 4);
      f0 = ((const float4*)bp)[0]; f1 = ((const float4*)bp)[1];
      f2 = ((const float4*)bp)[2]; f3 = ((const float4*)bp)[3];
      short* brow = Bsl + srow * LDR + (shalf << 4);
      *(bf16x8*)(brow)     = pack8(f0, f1);
      *(bf16x8*)(brow + 8) = pack8(f2, f3);
    }
    __syncthreads();
    bf16x8 af[4], bfr[4];
#pragma unroll
    for (int i = 0; i < 4; ++i) {
      af[i]  = *(const bf16x8*)(Asl + ((wr << 6) + (i << 4) + m16) * LDR + (g4 << 3));
      bfr[i] = *(const bf16x8*)(Bsl + ((wc << 6) + (i << 4) + m16) * LDR + (g4 << 3));
    }
#pragma unroll
    for (int i = 0; i < 4; ++i)
#pragma unroll
      for (int j = 0; j < 4; ++j)
        acc[i][j] = __builtin_amdgcn_mfma_f32_16x16x32_bf16(af[i], bfr[j], acc[i][j], 0, 0, 0);
    __syncthreads();
  }
#pragma unroll
  for (int i = 0; i < 4; ++i)
#pragma unroll
    for (int j = 0; j < 4; ++j) {
      const int col = bn + (wc << 6) + (j << 4) + m16;
      const float bv = b_attn[col];
#pragma unroll
      for (int q = 0; q < 4; ++q) {
        const int row = bm + (wr << 6) + (i << 4) + (g4 << 2) + q;
        histt[(size_t)row * N + col] = tanhf(acc[i][j][q] + bv);
      }
    }
}

// ---------------- persistent GRU (round-7 proven): flag protocol, L3-direct atomics ----------------
// 64 blocks x 128 threads (2 cooperating waves). block = (chunk c = bid>>2, group g = bid&3).
// Block owns j in [32c, 32c+32), wave tt owns 16 of them; batches [16g, 16g+16).
// W_hh slice in LDS as bf16 (96 KB), XOR-swizzled; wave tt touches only its 3 slabs.
// producer: 8B atomic h stores -> s_waitcnt vmcnt(0) -> __syncthreads -> flag store (1/block)
// consumer: relaxed 16-flag poll -> 8B atomic h loads (fresh from L3 by construction)
// gx loads issued BEFORE the poll so HBM latency hides under the wait.
__global__ __launch_bounds__(128)
void gru_persist(const float* __restrict__ gx, const float* __restrict__ W_hh,
                 const float* __restrict__ b_hh, const int* __restrict__ lens,
                 short* __restrict__ h_bf, float* __restrict__ lastb,
                 unsigned int* __restrict__ flags) {
  __shared__ short wlds[6 * 16 * 512];   // 96 KB
  const int tid = threadIdx.x;
  const int lane = tid & 63, tt = tid >> 6;
  const int bid = blockIdx.x;
  const int c = bid >> 2, grp = bid & 3;
  const int j0 = (c << 5) + (tt << 4);
  const int b0 = grp << 4;
  const int m16 = lane & 15, g4 = lane >> 4;

  for (int gi = 0; gi < 3; ++gi) {
    const float* wg = W_hh + (size_t)(gi * 512 + j0) * 512;
    short* slab = wlds + (((gi << 1) + tt) << 13);
    for (int r = 0; r < 16; ++r) {
      int k = lane << 3;
      const float4* src = (const float4*)(wg + (size_t)r * 512 + k);
      int off = ((r << 9) + k) ^ ((r & 7) << 3);
      *(bf16x8*)(slab + off) = pack8(src[0], src[1]);
    }
  }
  __syncthreads();

  const int bcol = b0 + m16;
  const int jr = j0 + (g4 << 2);
  const f32x4 bhr = *(const f32x4*)&b_hh[jr];
  const f32x4 bhz = *(const f32x4*)&b_hh[512 + jr];
  const f32x4 bhn = *(const f32x4*)&b_hh[1024 + jr];
  const int lenb = lens[bcol];
  f32x4 hprev = {0.f, 0.f, 0.f, 0.f};

  unsigned int* gflags = flags + (grp << 8);
  unsigned int* ownflag = gflags + (c << 4);

  for (int t = 0; t < 128; ++t) {
    const float* gxb = gx + ((size_t)t * 64 + bcol) * 1536;
    f32x4 gr = *(const f32x4*)(gxb + jr);
    f32x4 gz = *(const f32x4*)(gxb + 512 + jr);
    f32x4 gn = *(const f32x4*)(gxb + 1024 + jr);
    f32x4 ar = {0.f, 0.f, 0.f, 0.f}, az = ar, an = ar;
    if (t) {
      unsigned tgt = (unsigned)t;
      while (true) {
        unsigned f = tgt;
        if (lane < 16)
          f = __hip_atomic_load(gflags + (lane << 4), __ATOMIC_RELAXED, __HIP_MEMORY_SCOPE_AGENT);
        if (__all((int)(f >= tgt))) break;
      }
      asm volatile("" ::: "memory");

      const u64* hp = (const u64*)(h_bf + ((t & 1) << 15) + (size_t)bcol * 512 + (g4 << 3));
      u64 hu[32];
#pragma unroll
      for (int ks = 0; ks < 16; ++ks) {
        hu[2 * ks]     = __hip_atomic_load(hp + ks * 8,     __ATOMIC_RELAXED, __HIP_MEMORY_SCOPE_AGENT);
        hu[2 * ks + 1] = __hip_atomic_load(hp + ks * 8 + 1, __ATOMIC_RELAXED, __HIP_MEMORY_SCOPE_AGENT);
      }
#define GRU_MFMA(ks)                                                                 \
      {                                                                              \
        u64x2 p; p[0] = hu[2 * (ks)]; p[1] = hu[2 * (ks) + 1];                       \
        bf16x8 hf = __builtin_bit_cast(bf16x8, p);                                   \
        int off = ((m16 << 9) + ((ks) << 5) + (g4 << 3)) ^ ((m16 & 7) << 3);         \
        ar = __builtin_amdgcn_mfma_f32_16x16x32_bf16(*(const bf16x8*)(wlds + ((0 + tt) << 13) + off), hf, ar, 0, 0, 0); \
        az = __builtin_amdgcn_mfma_f32_16x16x32_bf16(*(const bf16x8*)(wlds + ((2 + tt) << 13) + off), hf, az, 0, 0, 0); \
        an = __builtin_amdgcn_mfma_f32_16x16x32_bf16(*(const bf16x8*)(wlds + ((4 + tt) << 13) + off), hf, an, 0, 0, 0); \
      }
      GRU_MFMA(0)  GRU_MFMA(1)  GRU_MFMA(2)  GRU_MFMA(3)
      GRU_MFMA(4)  GRU_MFMA(5)  GRU_MFMA(6)  GRU_MFMA(7)
      GRU_MFMA(8)  GRU_MFMA(9)  GRU_MFMA(10) GRU_MFMA(11)
      GRU_MFMA(12) GRU_MFMA(13) GRU_MFMA(14) GRU_MFMA(15)
#undef GRU_MFMA
    }
    u16x4 hw;
#pragma unroll
    for (int q = 0; q < 4; ++q) {
      float r = 1.f / (1.f + __expf(-(gr[q] + ar[q] + bhr[q])));
      float z = 1.f / (1.f + __expf(-(gz[q] + az[q] + bhz[q])));
      float xn = gn[q] + r * (an[q] + bhn[q]);
      float n = 1.f - 2.f / (__expf(2.f * xn) + 1.f);
      float hv = (1.f - z) * n + z * hprev[q];
      hprev[q] = hv;
      hw[q] = f2bf(hv);
    }
    __hip_atomic_store((u64*)(h_bf + ((~t & 1) << 15) + (size_t)bcol * 512 + jr),
                       __builtin_bit_cast(u64, hw),
                       __ATOMIC_RELAXED, __HIP_MEMORY_SCOPE_AGENT);
    if (t == lenb - 1) {
      *(f32x4*)(lastb + (size_t)bcol * 512 + jr) = hprev;
    }
    if (t < 127) {
      asm volatile("s_waitcnt vmcnt(0)" ::: "memory");
      __syncthreads();
      if (tid == 0)
        __hip_atomic_store(ownflag, (unsigned)(t + 1), __ATOMIC_RELAXED, __HIP_MEMORY_SCOPE_AGENT);
    }
  }
}

// ---------------- attention: energies, softmax, context (one block per b) ----------------
__global__ __launch_bounds__(256)
void attn_ctx(const float* __restrict__ histt, const float* __restrict__ last,
              float* __restrict__ ctx) {
  int b = blockIdx.x, tid = threadIdx.x;
  __shared__ float ls[512];
  __shared__ float w[256];
  __shared__ float red[256];
  ((float2*)ls)[tid] = ((const float2*)(last + (size_t)b * 512))[tid];
  __syncthreads();
  const float* hb = histt + (size_t)b * 256 * 512;
  const float* hrow = hb + (size_t)tid * 512;
  float acc = 0.f;
  for (int k = 0; k < 512; k += 4) {
    float4 h4 = *(const float4*)(hrow + k);
    acc += ls[k] * h4.x + ls[k + 1] * h4.y + ls[k + 2] * h4.z + ls[k + 3] * h4.w;
  }
  red[tid] = acc;
  __syncthreads();
  for (int s = 128; s; s >>= 1) {
    if (tid < s) red[tid] = fmaxf(red[tid], red[tid + s]);
    __syncthreads();
  }
  float m = red[0];
  __syncthreads();
  float ex = expf(acc - m);
  w[tid] = ex; red[tid] = ex;
  __syncthreads();
  for (int s = 128; s; s >>= 1) {
    if (tid < s) red[tid] += red[tid + s];
    __syncthreads();
  }
  float inv = 1.f / red[0];
  float c0 = 0.f, c1 = 0.f;
  for (int n = 0; n < 256; ++n) {
    float wn = w[n];
    c0 += wn * hb[(size_t)n * 512 + tid];
    c1 += wn * hb[(size_t)n * 512 + tid + 256];
  }
  ctx[(size_t)b * 512 + tid]       = c0 * inv;
  ctx[(size_t)b * 512 + tid + 256] = c1 * inv;
}

// ---------------- final: y[b][u] = [last|ctx|last] . W_final[u] + b_final[u] ----------------
// Padded LDS (stride 132, float4-aligned) + vectorized b128 LDS reads.
__global__ __launch_bounds__(256)
void final_gemm(const float* __restrict__ last, const float* __restrict__ ctx,
                const float* __restrict__ Wf, const float* __restrict__ bf,
                float* __restrict__ y) {
  __shared__ float s[64][132];
  const int tid = threadIdx.x;
  const int u0 = blockIdx.x << 3;
  const int ul = tid >> 6, b = tid & 63;
  float acc0 = 0.f, acc1 = 0.f;
  for (int kc = 0; kc < 12; ++kc) {
    __syncthreads();
    for (int i = tid; i < 2048; i += 256) {
      int rb = i >> 5, cc = (i & 31) << 2;
      int k = kc * 128 + cc;
      const float* src = (k < 512) ? (last + (size_t)rb * 512 + k)
                       : (k < 1024) ? (ctx + (size_t)rb * 512 + k - 512)
                                    : (last + (size_t)rb * 512 + k - 1024);
      *(float4*)&s[rb][cc] = *(const float4*)src;
    }
    __syncthreads();
#pragma unroll
    for (int uu = 0; uu < 2; ++uu) {
      int u = u0 + ul + uu * 4;
      const float* wrow = Wf + (size_t)u * 1536 + kc * 128;
      float a = 0.f;
#pragma unroll 8
      for (int c = 0; c < 128; c += 4) {
        float4 w4 = *(const float4*)(wrow + c);
        float4 s4 = *(const float4*)&s[b][c];
        a += w4.x * s4.x + w4.y * s4.y + w4.z * s4.z + w4.w * s4.w;
      }
      if (uu == 0) acc0 += a; else acc1 += a;
    }
  }
  int u = u0 + ul;
  y[(size_t)b * 5000 + u]     = acc0 + bf[u];
  y[(size_t)b * 5000 + u + 4] = acc1 + bf[u + 4];
}

// ---------------- broadcast y (B,5000) -> out (B,T,5000) ----------------
__global__ void broadcast_y(const float* __restrict__ y, float* __restrict__ out) {
  int bt = blockIdx.x;
  const float4* src = (const float4*)(y + (size_t)(bt >> 7) * 5000);
  float4* dst = (float4*)(out + (size_t)bt * 5000);
  for (int i = threadIdx.x; i < 1250; i += 256) dst[i] = src[i];
}

extern "C" void kernel_launch(void* const* d_in, const int* in_sizes, int n_in,
                              void* d_out, int out_size, void* d_ws, size_t ws_size,
                              hipStream_t stream) {
  const int* loc  = (const int*)d_in[0];
  const int* tim  = (const int*)d_in[1];
  const int* lens = (const int*)d_in[2];
  const int* hloc = (const int*)d_in[3];
  const int* htim = (const int*)d_in[4];
  const int* huid = (const int*)d_in[5];
  // d_in[6] = group_size (constant 4, baked in)
  const float* eloc    = (const float*)d_in[7];
  const float* etim    = (const float*)d_in[8];
  const float* euid    = (const float*)d_in[9];
  const float* W_attn  = (const float*)d_in[10];
  const float* b_attn  = (const float*)d_in[11];
  const float* W_ih    = (const float*)d_in[12];
  const float* b_ih    = (const float*)d_in[13];
  const float* W_hh    = (const float*)d_in[14];
  const float* b_hh    = (const float*)d_in[15];
  const float* W_final = (const float*)d_in[16];
  const float* b_final = (const float*)d_in[17];
  float* out = (float*)d_out;
  char* ws = (char*)d_ws;

  // workspace layout (bytes)
  float* gx    = (float*)(ws + 0ull);            // 8192*1536*4 = 50,331,648
  float* histt = (float*)(ws + 50331648ull);     // 16384*512*4 = 33,554,432
  float* lastb = (float*)(ws + 83886080ull);     // 64*512*4 = 131,072
  float* ctx   = (float*)(ws + 84017152ull);     // 131,072
  float* yv    = (float*)(ws + 84148224ull);     // 64*5000*4 = 1,280,000
  short* h_bf  = (short*)(ws + 85428224ull);     // 2*64*512*2 = 131,072
  unsigned int* flags = (unsigned int*)(ws + 85559296ull);   // 4 grp x 16 x 64B = 4096

  gemm_gx_f<<<dim3(12, 64), 256, 0, stream>>>(loc, tim, eloc, etim, W_ih, b_ih, gx);
  gemm_attn_f<<<dim3(4, 128), 256, 0, stream>>>(hloc, htim, huid, eloc, etim, euid,
                                                W_attn, b_attn, histt);

  hipMemsetAsync(flags, 0, 4096, stream);
  gru_persist<<<64, 128, 0, stream>>>(gx, W_hh, b_hh, lens, h_bf, lastb, flags);

  attn_ctx<<<64, 256, 0, stream>>>(histt, lastb, ctx);
  final_gemm<<<625, 256, 0, stream>>>(lastb, ctx, W_final, b_final, yv);
  broadcast_y<<<8192, 256, 0, stream>>>(yv, out);
}

// Round 11
// 645.632 us; speedup vs baseline: 1.4571x; 1.0618x over previous
//
#include <hip/hip_runtime.h>
#include <hip/hip_bf16.h>

// Sizes (fixed): B=64 T=128 HID=512 LOC_EMB=256 TIM_EMB=64 UID_EMB=128
// L_HIST=1024 G=4, K_x=320, K_attn=448, N_gates=1536, UID_SIZE=5000

typedef __attribute__((ext_vector_type(8))) short bf16x8;
typedef __attribute__((ext_vector_type(4))) float f32x4;
typedef __attribute__((ext_vector_type(4))) unsigned short u16x4;
typedef __attribute__((ext_vector_type(2))) unsigned long long u64x2;
typedef unsigned long long u64;

__device__ inline unsigned short f2bf(float x) {
  __hip_bfloat16 b = __float2bfloat16(x);
  return __builtin_bit_cast(unsigned short, b);
}
__device__ inline bf16x8 pack8(float4 a, float4 b) {
  bf16x8 w;
  w[0]=(short)f2bf(a.x); w[1]=(short)f2bf(a.y); w[2]=(short)f2bf(a.z); w[3]=(short)f2bf(a.w);
  w[4]=(short)f2bf(b.x); w[5]=(short)f2bf(b.y); w[6]=(short)f2bf(b.z); w[7]=(short)f2bf(b.w);
  return w;
}

// ---------------- gather-fused bf16 GEMM: gx = [emb_loc|emb_tim] @ W_ih^T + b_ih ----------------
// grid (12, 64): 128x128 tile, BK=32, 4 waves, padded LDS (stride 40 shorts).
__global__ __launch_bounds__(256)
void gemm_gx_f(const int* __restrict__ loc, const int* __restrict__ tim,
               const float* __restrict__ eloc, const float* __restrict__ etim,
               const float* __restrict__ W_ih, const float* __restrict__ b_ih,
               float* __restrict__ gx) {
  constexpr int LDR = 40, K = 320, N = 1536;
  __shared__ short Asl[128 * LDR];
  __shared__ short Bsl[128 * LDR];
  const int tid = threadIdx.x;
  const int lane = tid & 63, wid = tid >> 6;
  const int wr = wid >> 1, wc = wid & 1;
  const int m16 = lane & 15, g4 = lane >> 4;
  const int bm = blockIdx.y * 128, bn = blockIdx.x * 128;
  const int srow = tid >> 1, shalf = tid & 1;
  f32x4 acc[4][4] = {};
  for (int k0 = 0; k0 < K; k0 += 32) {
    {
      const int grow = bm + srow;
      const int t = grow >> 6, b = grow & 63;
      const float* ap = (k0 < 256)
        ? eloc + (size_t)loc[b * 128 + t] * 256 + k0 + (shalf << 4)
        : etim + (size_t)tim[b * 128 + t] * 64 + (k0 - 256) + (shalf << 4);
      float4 f0 = ((const float4*)ap)[0], f1 = ((const float4*)ap)[1];
      float4 f2 = ((const float4*)ap)[2], f3 = ((const float4*)ap)[3];
      short* arow = Asl + srow * LDR + (shalf << 4);
      *(bf16x8*)(arow)     = pack8(f0, f1);
      *(bf16x8*)(arow + 8) = pack8(f2, f3);
      const float* bp = W_ih + (size_t)(bn + srow) * K + k0 + (shalf << 4);
      f0 = ((const float4*)bp)[0]; f1 = ((const float4*)bp)[1];
      f2 = ((const float4*)bp)[2]; f3 = ((const float4*)bp)[3];
      short* brow = Bsl + srow * LDR + (shalf << 4);
      *(bf16x8*)(brow)     = pack8(f0, f1);
      *(bf16x8*)(brow + 8) = pack8(f2, f3);
    }
    __syncthreads();
    bf16x8 af[4], bfr[4];
#pragma unroll
    for (int i = 0; i < 4; ++i) {
      af[i]  = *(const bf16x8*)(Asl + ((wr << 6) + (i << 4) + m16) * LDR + (g4 << 3));
      bfr[i] = *(const bf16x8*)(Bsl + ((wc << 6) + (i << 4) + m16) * LDR + (g4 << 3));
    }
#pragma unroll
    for (int i = 0; i < 4; ++i)
#pragma unroll
      for (int j = 0; j < 4; ++j)
        acc[i][j] = __builtin_amdgcn_mfma_f32_16x16x32_bf16(af[i], bfr[j], acc[i][j], 0, 0, 0);
    __syncthreads();
  }
#pragma unroll
  for (int i = 0; i < 4; ++i)
#pragma unroll
    for (int j = 0; j < 4; ++j) {
      const int col = bn + (wc << 6) + (j << 4) + m16;
      const float bv = b_ih[col];
#pragma unroll
      for (int q = 0; q < 4; ++q) {
        const int row = bm + (wr << 6) + (i << 4) + (g4 << 2) + q;
        gx[(size_t)row * N + col] = acc[i][j][q] + bv;
      }
    }
}

// ---------------- combined: GRU (blocks 0..63) + gather-fused attn GEMM (blocks 64..191) ----------------
// No data/pacing dependence between the roles: histt is consumed only after this kernel.
// GRU role: round-7/10 proven protocol, 2 active waves (tid<128) + 2 idle waves
// (idle waves execute the exact same __syncthreads count: 1 + 127 = 128).
// attn-GEMM role: 512 tiles (4 nt x 128 yt) strided over 128 blocks; 96 KB kernel LDS
// caps it at 1 block/CU, but it is fully hidden inside the GRU window.
__global__ __launch_bounds__(256)
void gru_attn(const float* __restrict__ gx, const float* __restrict__ W_hh,
              const float* __restrict__ b_hh, const int* __restrict__ lens,
              short* __restrict__ h_bf, float* __restrict__ lastb,
              unsigned int* __restrict__ flags,
              const int* __restrict__ hloc, const int* __restrict__ htim,
              const int* __restrict__ huid,
              const float* __restrict__ eloc, const float* __restrict__ etim,
              const float* __restrict__ euid,
              const float* __restrict__ W_attn, const float* __restrict__ b_attn,
              float* __restrict__ histt) {
  __shared__ short smem[6 * 16 * 512];   // 96 KB shared by both roles
  const int bid = blockIdx.x;
  const int tid = threadIdx.x;

  if (bid < 64) {
    // ===================== GRU role =====================
    if (tid >= 128) {                    // idle waves: match barrier sequence exactly
      for (int t = 0; t < 128; ++t) __syncthreads();
      return;
    }
    const int lane = tid & 63, tt = tid >> 6;
    const int c = bid >> 2, grp = bid & 3;
    const int j0 = (c << 5) + (tt << 4);
    const int b0 = grp << 4;
    const int m16 = lane & 15, g4 = lane >> 4;

    for (int gi = 0; gi < 3; ++gi) {
      const float* wg = W_hh + (size_t)(gi * 512 + j0) * 512;
      short* slab = smem + (((gi << 1) + tt) << 13);
      for (int r = 0; r < 16; ++r) {
        int k = lane << 3;
        const float4* src = (const float4*)(wg + (size_t)r * 512 + k);
        int off = ((r << 9) + k) ^ ((r & 7) << 3);
        *(bf16x8*)(slab + off) = pack8(src[0], src[1]);
      }
    }
    __syncthreads();

    const int bcol = b0 + m16;
    const int jr = j0 + (g4 << 2);
    const f32x4 bhr = *(const f32x4*)&b_hh[jr];
    const f32x4 bhz = *(const f32x4*)&b_hh[512 + jr];
    const f32x4 bhn = *(const f32x4*)&b_hh[1024 + jr];
    const int lenb = lens[bcol];
    f32x4 hprev = {0.f, 0.f, 0.f, 0.f};

    unsigned int* gflags = flags + (grp << 8);
    unsigned int* ownflag = gflags + (c << 4);

    for (int t = 0; t < 128; ++t) {
      const float* gxb = gx + ((size_t)t * 64 + bcol) * 1536;
      f32x4 gr = *(const f32x4*)(gxb + jr);
      f32x4 gz = *(const f32x4*)(gxb + 512 + jr);
      f32x4 gn = *(const f32x4*)(gxb + 1024 + jr);
      f32x4 ar = {0.f, 0.f, 0.f, 0.f}, az = ar, an = ar;
      if (t) {
        unsigned tgt = (unsigned)t;
        while (true) {
          unsigned f = tgt;
          if (lane < 16)
            f = __hip_atomic_load(gflags + (lane << 4), __ATOMIC_RELAXED, __HIP_MEMORY_SCOPE_AGENT);
          if (__all((int)(f >= tgt))) break;
        }
        asm volatile("" ::: "memory");

        const u64* hp = (const u64*)(h_bf + ((t & 1) << 15) + (size_t)bcol * 512 + (g4 << 3));
        u64 hu[32];
#pragma unroll
        for (int ks = 0; ks < 16; ++ks) {
          hu[2 * ks]     = __hip_atomic_load(hp + ks * 8,     __ATOMIC_RELAXED, __HIP_MEMORY_SCOPE_AGENT);
          hu[2 * ks + 1] = __hip_atomic_load(hp + ks * 8 + 1, __ATOMIC_RELAXED, __HIP_MEMORY_SCOPE_AGENT);
        }
#define GRU_MFMA(ks)                                                                 \
        {                                                                            \
          u64x2 p; p[0] = hu[2 * (ks)]; p[1] = hu[2 * (ks) + 1];                     \
          bf16x8 hf = __builtin_bit_cast(bf16x8, p);                                 \
          int off = ((m16 << 9) + ((ks) << 5) + (g4 << 3)) ^ ((m16 & 7) << 3);       \
          ar = __builtin_amdgcn_mfma_f32_16x16x32_bf16(*(const bf16x8*)(smem + ((0 + tt) << 13) + off), hf, ar, 0, 0, 0); \
          az = __builtin_amdgcn_mfma_f32_16x16x32_bf16(*(const bf16x8*)(smem + ((2 + tt) << 13) + off), hf, az, 0, 0, 0); \
          an = __builtin_amdgcn_mfma_f32_16x16x32_bf16(*(const bf16x8*)(smem + ((4 + tt) << 13) + off), hf, an, 0, 0, 0); \
        }
        GRU_MFMA(0)  GRU_MFMA(1)  GRU_MFMA(2)  GRU_MFMA(3)
        GRU_MFMA(4)  GRU_MFMA(5)  GRU_MFMA(6)  GRU_MFMA(7)
        GRU_MFMA(8)  GRU_MFMA(9)  GRU_MFMA(10) GRU_MFMA(11)
        GRU_MFMA(12) GRU_MFMA(13) GRU_MFMA(14) GRU_MFMA(15)
#undef GRU_MFMA
      }
      u16x4 hw;
#pragma unroll
      for (int q = 0; q < 4; ++q) {
        float r = 1.f / (1.f + __expf(-(gr[q] + ar[q] + bhr[q])));
        float z = 1.f / (1.f + __expf(-(gz[q] + az[q] + bhz[q])));
        float xn = gn[q] + r * (an[q] + bhn[q]);
        float n = 1.f - 2.f / (__expf(2.f * xn) + 1.f);
        float hv = (1.f - z) * n + z * hprev[q];
        hprev[q] = hv;
        hw[q] = f2bf(hv);
      }
      __hip_atomic_store((u64*)(h_bf + ((~t & 1) << 15) + (size_t)bcol * 512 + jr),
                         __builtin_bit_cast(u64, hw),
                         __ATOMIC_RELAXED, __HIP_MEMORY_SCOPE_AGENT);
      if (t == lenb - 1) {
        *(f32x4*)(lastb + (size_t)bcol * 512 + jr) = hprev;
      }
      if (t < 127) {
        asm volatile("s_waitcnt vmcnt(0)" ::: "memory");
        __syncthreads();
        if (tid == 0)
          __hip_atomic_store(ownflag, (unsigned)(t + 1), __ATOMIC_RELAXED, __HIP_MEMORY_SCOPE_AGENT);
      }
    }
    return;
  }

  // ===================== attn GEMM role =====================
  constexpr int LDR = 40, K = 448, N = 512;
  short* Asl = smem;
  short* Bsl = smem + 128 * LDR;
  const int lane = tid & 63, wid = tid >> 6;
  const int wr = wid >> 1, wc = wid & 1;
  const int m16 = lane & 15, g4 = lane >> 4;
  const int srow = tid >> 1, shalf = tid & 1;
  for (int tile = bid - 64; tile < 512; tile += 128) {
    const int yt = tile >> 2, nt = tile & 3;
    const int bm = yt << 7, bn = nt << 7;
    f32x4 acc[4][4] = {};
    for (int k0 = 0; k0 < K; k0 += 32) {
      {
        const int grow = bm + srow;
        const int b = grow >> 8, n = grow & 255;
        const int base = b * 1024 + (n << 2);
        float4 f0, f1, f2, f3;
        if (k0 < 256) {
          const float* ap = eloc + (size_t)hloc[base] * 256 + k0 + (shalf << 4);
          f0 = ((const float4*)ap)[0]; f1 = ((const float4*)ap)[1];
          f2 = ((const float4*)ap)[2]; f3 = ((const float4*)ap)[3];
        } else if (k0 < 320) {
          const float* ap = etim + (size_t)htim[base] * 64 + (k0 - 256) + (shalf << 4);
          f0 = ((const float4*)ap)[0]; f1 = ((const float4*)ap)[1];
          f2 = ((const float4*)ap)[2]; f3 = ((const float4*)ap)[3];
        } else {
          const int cu = (k0 - 320) + (shalf << 4);
          const float4* u0 = (const float4*)(euid + (size_t)huid[base + 0] * 128 + cu);
          const float4* u1 = (const float4*)(euid + (size_t)huid[base + 1] * 128 + cu);
          const float4* u2 = (const float4*)(euid + (size_t)huid[base + 2] * 128 + cu);
          const float4* u3 = (const float4*)(euid + (size_t)huid[base + 3] * 128 + cu);
#define AVG4(idx, dst) { float4 a=u0[idx],b4=u1[idx],c4=u2[idx],d4=u3[idx];            \
          dst.x=0.25f*(a.x+b4.x+c4.x+d4.x); dst.y=0.25f*(a.y+b4.y+c4.y+d4.y);         \
          dst.z=0.25f*(a.z+b4.z+c4.z+d4.z); dst.w=0.25f*(a.w+b4.w+c4.w+d4.w); }
          AVG4(0, f0) AVG4(1, f1) AVG4(2, f2) AVG4(3, f3)
#undef AVG4
        }
        short* arow = Asl + srow * LDR + (shalf << 4);
        *(bf16x8*)(arow)     = pack8(f0, f1);
        *(bf16x8*)(arow + 8) = pack8(f2, f3);
        const float* bp = W_attn + (size_t)(bn + srow) * K + k0 + (shalf << 4);
        f0 = ((const float4*)bp)[0]; f1 = ((const float4*)bp)[1];
        f2 = ((const float4*)bp)[2]; f3 = ((const float4*)bp)[3];
        short* brow = Bsl + srow * LDR + (shalf << 4);
        *(bf16x8*)(brow)     = pack8(f0, f1);
        *(bf16x8*)(brow + 8) = pack8(f2, f3);
      }
      __syncthreads();
      bf16x8 af[4], bfr[4];
#pragma unroll
      for (int i = 0; i < 4; ++i) {
        af[i]  = *(const bf16x8*)(Asl + ((wr << 6) + (i << 4) + m16) * LDR + (g4 << 3));
        bfr[i] = *(const bf16x8*)(Bsl + ((wc << 6) + (i << 4) + m16) * LDR + (g4 << 3));
      }
#pragma unroll
      for (int i = 0; i < 4; ++i)
#pragma unroll
        for (int j = 0; j < 4; ++j)
          acc[i][j] = __builtin_amdgcn_mfma_f32_16x16x32_bf16(af[i], bfr[j], acc[i][j], 0, 0, 0);
      __syncthreads();
    }
#pragma unroll
    for (int i = 0; i < 4; ++i)
#pragma unroll
      for (int j = 0; j < 4; ++j) {
        const int col = bn + (wc << 6) + (j << 4) + m16;
        const float bv = b_attn[col];
#pragma unroll
        for (int q = 0; q < 4; ++q) {
          const int row = bm + (wr << 6) + (i << 4) + (g4 << 2) + q;
          histt[(size_t)row * N + col] = tanhf(acc[i][j][q] + bv);
        }
      }
  }
}

// ---------------- attention: energies, softmax, context (one block per b) ----------------
__global__ __launch_bounds__(256)
void attn_ctx(const float* __restrict__ histt, const float* __restrict__ last,
              float* __restrict__ ctx) {
  int b = blockIdx.x, tid = threadIdx.x;
  __shared__ float ls[512];
  __shared__ float w[256];
  __shared__ float red[256];
  ((float2*)ls)[tid] = ((const float2*)(last + (size_t)b * 512))[tid];
  __syncthreads();
  const float* hb = histt + (size_t)b * 256 * 512;
  const float* hrow = hb + (size_t)tid * 512;
  float acc = 0.f;
  for (int k = 0; k < 512; k += 4) {
    float4 h4 = *(const float4*)(hrow + k);
    acc += ls[k] * h4.x + ls[k + 1] * h4.y + ls[k + 2] * h4.z + ls[k + 3] * h4.w;
  }
  red[tid] = acc;
  __syncthreads();
  for (int s = 128; s; s >>= 1) {
    if (tid < s) red[tid] = fmaxf(red[tid], red[tid + s]);
    __syncthreads();
  }
  float m = red[0];
  __syncthreads();
  float ex = expf(acc - m);
  w[tid] = ex; red[tid] = ex;
  __syncthreads();
  for (int s = 128; s; s >>= 1) {
    if (tid < s) red[tid] += red[tid + s];
    __syncthreads();
  }
  float inv = 1.f / red[0];
  float c0 = 0.f, c1 = 0.f;
  for (int n = 0; n < 256; ++n) {
    float wn = w[n];
    c0 += wn * hb[(size_t)n * 512 + tid];
    c1 += wn * hb[(size_t)n * 512 + tid + 256];
  }
  ctx[(size_t)b * 512 + tid]       = c0 * inv;
  ctx[(size_t)b * 512 + tid + 256] = c1 * inv;
}

// ---------------- final: y[b][u] = [last|ctx|last] . W_final[u] + b_final[u] ----------------
__global__ __launch_bounds__(256)
void final_gemm(const float* __restrict__ last, const float* __restrict__ ctx,
                const float* __restrict__ Wf, const float* __restrict__ bf,
                float* __restrict__ y) {
  __shared__ float s[64][132];
  const int tid = threadIdx.x;
  const int u0 = blockIdx.x << 3;
  const int ul = tid >> 6, b = tid & 63;
  float acc0 = 0.f, acc1 = 0.f;
  for (int kc = 0; kc < 12; ++kc) {
    __syncthreads();
    for (int i = tid; i < 2048; i += 256) {
      int rb = i >> 5, cc = (i & 31) << 2;
      int k = kc * 128 + cc;
      const float* src = (k < 512) ? (last + (size_t)rb * 512 + k)
                       : (k < 1024) ? (ctx + (size_t)rb * 512 + k - 512)
                                    : (last + (size_t)rb * 512 + k - 1024);
      *(float4*)&s[rb][cc] = *(const float4*)src;
    }
    __syncthreads();
#pragma unroll
    for (int uu = 0; uu < 2; ++uu) {
      int u = u0 + ul + uu * 4;
      const float* wrow = Wf + (size_t)u * 1536 + kc * 128;
      float a = 0.f;
#pragma unroll 8
      for (int c = 0; c < 128; c += 4) {
        float4 w4 = *(const float4*)(wrow + c);
        float4 s4 = *(const float4*)&s[b][c];
        a += w4.x * s4.x + w4.y * s4.y + w4.z * s4.z + w4.w * s4.w;
      }
      if (uu == 0) acc0 += a; else acc1 += a;
    }
  }
  int u = u0 + ul;
  y[(size_t)b * 5000 + u]     = acc0 + bf[u];
  y[(size_t)b * 5000 + u + 4] = acc1 + bf[u + 4];
}

// ---------------- broadcast y (B,5000) -> out (B,T,5000) ----------------
__global__ void broadcast_y(const float* __restrict__ y, float* __restrict__ out) {
  int bt = blockIdx.x;
  const float4* src = (const float4*)(y + (size_t)(bt >> 7) * 5000);
  float4* dst = (float4*)(out + (size_t)bt * 5000);
  for (int i = threadIdx.x; i < 1250; i += 256) dst[i] = src[i];
}

extern "C" void kernel_launch(void* const* d_in, const int* in_sizes, int n_in,
                              void* d_out, int out_size, void* d_ws, size_t ws_size,
                              hipStream_t stream) {
  const int* loc  = (const int*)d_in[0];
  const int* tim  = (const int*)d_in[1];
  const int* lens = (const int*)d_in[2];
  const int* hloc = (const int*)d_in[3];
  const int* htim = (const int*)d_in[4];
  const int* huid = (const int*)d_in[5];
  // d_in[6] = group_size (constant 4, baked in)
  const float* eloc    = (const float*)d_in[7];
  const float* etim    = (const float*)d_in[8];
  const float* euid    = (const float*)d_in[9];
  const float* W_attn  = (const float*)d_in[10];
  const float* b_attn  = (const float*)d_in[11];
  const float* W_ih    = (const float*)d_in[12];
  const float* b_ih    = (const float*)d_in[13];
  const float* W_hh    = (const float*)d_in[14];
  const float* b_hh    = (const float*)d_in[15];
  const float* W_final = (const float*)d_in[16];
  const float* b_final = (const float*)d_in[17];
  float* out = (float*)d_out;
  char* ws = (char*)d_ws;

  // workspace layout (bytes)
  float* gx    = (float*)(ws + 0ull);            // 8192*1536*4 = 50,331,648
  float* histt = (float*)(ws + 50331648ull);     // 16384*512*4 = 33,554,432
  float* lastb = (float*)(ws + 83886080ull);     // 64*512*4 = 131,072
  float* ctx   = (float*)(ws + 84017152ull);     // 131,072
  float* yv    = (float*)(ws + 84148224ull);     // 64*5000*4 = 1,280,000
  short* h_bf  = (short*)(ws + 85428224ull);     // 2*64*512*2 = 131,072
  unsigned int* flags = (unsigned int*)(ws + 85559296ull);   // 4 grp x 16 x 64B = 4096

  hipMemsetAsync(flags, 0, 4096, stream);        // off the critical path (before gemm)
  gemm_gx_f<<<dim3(12, 64), 256, 0, stream>>>(loc, tim, eloc, etim, W_ih, b_ih, gx);

  gru_attn<<<192, 256, 0, stream>>>(gx, W_hh, b_hh, lens, h_bf, lastb, flags,
                                    hloc, htim, huid, eloc, etim, euid,
                                    W_attn, b_attn, histt);

  attn_ctx<<<64, 256, 0, stream>>>(histt, lastb, ctx);
  final_gemm<<<625, 256, 0, stream>>>(lastb, ctx, W_final, b_final, yv);
  broadcast_y<<<8192, 256, 0, stream>>>(yv, out);
}